// Round 1
// baseline (292.438 us; speedup 1.0000x reference)
//
#include <hip/hip_runtime.h>

// Problem constants (fixed by the reference's setup_inputs):
//   EMB = 64 floats per embedding row (16 float4), HIST = 50 slots per row.
#define EMB4 16  // float4 per embedding row

// Native Clang vector type: __builtin_nontemporal_load/store rejects HIP's
// float4 (a HIP_vector_type class); ext_vector_type is accepted and emits the
// same global_load/store_dwordx4, with the nt cache hint.
typedef float vfloat4 __attribute__((ext_vector_type(4)));

// Kernel 1: CSR row offsets from the sorted positions array.
// One thread per row r in [0, batch]; row_start[r] = lower_bound(pos, r).
// Positions (1.6 MB) are fully L2-cached; ~19-step binary search, massively
// parallel (65 blocks, ~3 us total).
__global__ void build_row_starts(const int* __restrict__ pos, int n, int batch,
                                 int* __restrict__ row_start) {
    int r = blockIdx.x * blockDim.x + threadIdx.x;
    if (r > batch) return;
    if (r == batch) { row_start[r] = n; return; }
    int lo = 0, hi = n;
    while (lo < hi) {
        int mid = (lo + hi) >> 1;
        if (pos[mid] < r) lo = mid + 1; else hi = mid;
    }
    row_start[r] = lo;
}

// Kernel 2 (restructured this round): ONE WAVE PER ROW, copy/zero phases split.
//  - Previous version: one 256-thread block per row, 3.125 iters/thread with a
//    per-iteration `q < valid_q4` select. Profile showed it below the fill
//    kernels' 6.6 TB/s, suggesting poor pipelining / little per-wave ILP.
//  - Now: wave w owns row w. Each lane walks q = lane, lane+64, ... (12.5
//    iters): first a branch-free copy loop over the valid prefix, then a
//    branch-free zero loop for the tail. Lane residue classes partition the
//    800 float4s exactly, and each lane crosses from copy to zero at its own
//    boundary, so every q4 is written exactly once (no overlap, no gap).
//  - #pragma unroll 4 lets the compiler keep several NT loads in flight
//    before the dependent stores. Traffic is unchanged (read 104.9 MB,
//    write 209.7 MB — the minimum).
__global__ void __launch_bounds__(256)
fill_out_wave(const vfloat4* __restrict__ emb,
              const int* __restrict__ row_start,
              vfloat4* __restrict__ out,
              int hist, int batch) {
    const int row  = blockIdx.x * (blockDim.x >> 6) + (threadIdx.x >> 6);
    if (row >= batch) return;
    const int lane = threadIdx.x & 63;
    // row is wave-uniform; readfirstlane pins the bounds in SGPRs so the
    // address bases below are scalar.
    const int s   = __builtin_amdgcn_readfirstlane(row_start[row]);
    const int e   = __builtin_amdgcn_readfirstlane(row_start[row + 1]);
    int cnt = e - s;
    if (cnt > hist) cnt = hist;            // mode="drop" semantics
    const int q4_per_row = hist * EMB4;    // 800
    vfloat4* __restrict__ orow = out + (size_t)row * q4_per_row;
    const vfloat4* __restrict__ erow = emb + (size_t)s * EMB4;
    const int valid_q4 = cnt << 4;         // first valid_q4 float4s are copies

    int q = lane;
    // Copy phase: pure load->store stream, no per-iteration select.
    #pragma unroll 4
    for (; q < valid_q4; q += 64) {
        vfloat4 v = __builtin_nontemporal_load(&erow[q]);
        __builtin_nontemporal_store(v, &orow[q]);
    }
    // Zero phase: pure store stream. Each lane resumes from its own q, so the
    // union over lanes covers exactly [valid_q4, 800) with no double-writes.
    const vfloat4 z = (vfloat4)(0.f);
    #pragma unroll 4
    for (; q < q4_per_row; q += 64) {
        __builtin_nontemporal_store(z, &orow[q]);
    }
}

// Fallback if d_ws is too small: per-block binary search (thread 0 -> shared).
__global__ void __launch_bounds__(256)
fill_out_search(const vfloat4* __restrict__ emb,
                const int* __restrict__ pos, int n,
                vfloat4* __restrict__ out, int hist) {
    __shared__ int sh_s, sh_cnt;
    const int row = blockIdx.x;
    if (threadIdx.x == 0) {
        int lo = 0, hi = n;
        while (lo < hi) { int m = (lo + hi) >> 1; if (pos[m] < row) lo = m + 1; else hi = m; }
        const int s = lo;
        int lo2 = s, hi2 = n;
        while (lo2 < hi2) { int m = (lo2 + hi2) >> 1; if (pos[m] < row + 1) lo2 = m + 1; else hi2 = m; }
        sh_s = s;
        sh_cnt = lo2 - s;
    }
    __syncthreads();
    const int s = sh_s;
    int cnt = sh_cnt;
    if (cnt > hist) cnt = hist;
    const int q4_per_row = hist * EMB4;
    vfloat4* __restrict__ orow = out + (size_t)row * q4_per_row;
    const vfloat4* __restrict__ erow = emb + (size_t)s * EMB4;
    const int valid_q4 = cnt << 4;
    for (int q = threadIdx.x; q < q4_per_row; q += 256) {
        vfloat4 v = (vfloat4)(0.f);
        if (q < valid_q4) v = __builtin_nontemporal_load(&erow[q]);
        __builtin_nontemporal_store(v, &orow[q]);
    }
}

extern "C" void kernel_launch(void* const* d_in, const int* in_sizes, int n_in,
                              void* d_out, int out_size, void* d_ws, size_t ws_size,
                              hipStream_t stream) {
    const vfloat4* emb4 = (const vfloat4*)d_in[0];
    const int* pos = (const int*)d_in[1];
    // batch_size / hist_len are device-resident scalars (d_in[2]/d_in[3]);
    // cannot be read host-side under graph capture. hist is fixed at 50 by
    // the reference; batch follows from out_size.
    const int hist = 50;
    const int n = in_sizes[1];                 // 409600 valid entries
    const int batch = out_size / (hist * 64);  // 16384

    vfloat4* out4 = (vfloat4*)d_out;

    if (ws_size >= (size_t)(batch + 1) * sizeof(int)) {
        int* row_start = (int*)d_ws;
        build_row_starts<<<(batch + 1 + 255) / 256, 256, 0, stream>>>(pos, n, batch, row_start);
        // 4 waves (rows) per 256-thread block.
        fill_out_wave<<<(batch + 3) / 4, 256, 0, stream>>>(emb4, row_start, out4, hist, batch);
    } else {
        fill_out_search<<<batch, 256, 0, stream>>>(emb4, pos, n, out4, hist);
    }
}

// Round 2
// 287.042 us; speedup vs baseline: 1.0188x; 1.0188x over previous
//
#include <hip/hip_runtime.h>

// Problem constants (fixed by the reference's setup_inputs):
//   EMB = 64 floats per embedding row (16 float4), HIST = 50 slots per row.
#define EMB4 16  // float4 per embedding row

// Native Clang vector type: __builtin_nontemporal_load/store rejects HIP's
// float4 (a HIP_vector_type class); ext_vector_type is accepted and emits the
// same global_load/store_dwordx4, with the nt cache hint.
typedef float vfloat4 __attribute__((ext_vector_type(4)));

// ROOFLINE NOTE (round 1 A/B): this block-per-row form and a wave-per-row
// split-phase form measure within noise of each other (284.4 vs 292.4 us
// total), with identical minimal FETCH/WRITE. The timed window is dominated
// by the harness's ~839 MB re-poison fill (~128 us @ 6.5 TB/s) plus fixed
// overhead; kernel traffic (104.9 MB read + 209.7 MB write = ~50 us at
// 6.3 TB/s achievable) is already at the hand-computed minimum. Do not expect
// further gains from restructuring kernel 2.

// Kernel 1: CSR row offsets from the sorted positions array.
// One thread per row r in [0, batch]; row_start[r] = lower_bound(pos, r).
// Positions (1.6 MB) are fully L2-cached; ~19-step binary search, massively
// parallel (65 blocks, ~3 us total).
__global__ void build_row_starts(const int* __restrict__ pos, int n, int batch,
                                 int* __restrict__ row_start) {
    int r = blockIdx.x * blockDim.x + threadIdx.x;
    if (r > batch) return;
    if (r == batch) { row_start[r] = n; return; }
    int lo = 0, hi = n;
    while (lo < hi) {
        int mid = (lo + hi) >> 1;
        if (pos[mid] < r) lo = mid + 1; else hi = mid;
    }
    row_start[r] = lo;
}

// Kernel 2: one block per output row; every output float4 written exactly once
// (no zero-then-scatter: that would cost an extra 210 MB of writes).
// Streaming data gets non-temporal hints: emb is read once, out written once —
// caching either wastes L2/L3 capacity and write-allocate bandwidth.
__global__ void __launch_bounds__(256)
fill_out(const vfloat4* __restrict__ emb,
         const int* __restrict__ row_start,
         vfloat4* __restrict__ out,
         int hist) {
    const int row = blockIdx.x;
    const int s = row_start[row];          // wave-uniform -> scalar load
    int cnt = row_start[row + 1] - s;
    if (cnt > hist) cnt = hist;            // mode="drop" semantics
    const int q4_per_row = hist * EMB4;    // 800
    vfloat4* __restrict__ orow = out + (size_t)row * q4_per_row;
    const vfloat4* __restrict__ erow = emb + (size_t)s * EMB4;
    const int valid_q4 = cnt << 4;         // first valid_q4 float4s are copies
    for (int q = threadIdx.x; q < q4_per_row; q += 256) {
        vfloat4 v = (vfloat4)(0.f);
        if (q < valid_q4) v = __builtin_nontemporal_load(&erow[q]);
        __builtin_nontemporal_store(v, &orow[q]);
    }
}

// Fallback if d_ws is too small: per-block binary search (thread 0 -> shared).
__global__ void __launch_bounds__(256)
fill_out_search(const vfloat4* __restrict__ emb,
                const int* __restrict__ pos, int n,
                vfloat4* __restrict__ out, int hist) {
    __shared__ int sh_s, sh_cnt;
    const int row = blockIdx.x;
    if (threadIdx.x == 0) {
        int lo = 0, hi = n;
        while (lo < hi) { int m = (lo + hi) >> 1; if (pos[m] < row) lo = m + 1; else hi = m; }
        const int s = lo;
        int lo2 = s, hi2 = n;
        while (lo2 < hi2) { int m = (lo2 + hi2) >> 1; if (pos[m] < row + 1) lo2 = m + 1; else hi2 = m; }
        sh_s = s;
        sh_cnt = lo2 - s;
    }
    __syncthreads();
    const int s = sh_s;
    int cnt = sh_cnt;
    if (cnt > hist) cnt = hist;
    const int q4_per_row = hist * EMB4;
    vfloat4* __restrict__ orow = out + (size_t)row * q4_per_row;
    const vfloat4* __restrict__ erow = emb + (size_t)s * EMB4;
    const int valid_q4 = cnt << 4;
    for (int q = threadIdx.x; q < q4_per_row; q += 256) {
        vfloat4 v = (vfloat4)(0.f);
        if (q < valid_q4) v = __builtin_nontemporal_load(&erow[q]);
        __builtin_nontemporal_store(v, &orow[q]);
    }
}

extern "C" void kernel_launch(void* const* d_in, const int* in_sizes, int n_in,
                              void* d_out, int out_size, void* d_ws, size_t ws_size,
                              hipStream_t stream) {
    const vfloat4* emb4 = (const vfloat4*)d_in[0];
    const int* pos = (const int*)d_in[1];
    // batch_size / hist_len are device-resident scalars (d_in[2]/d_in[3]);
    // cannot be read host-side under graph capture. hist is fixed at 50 by
    // the reference; batch follows from out_size.
    const int hist = 50;
    const int n = in_sizes[1];                 // 409600 valid entries
    const int batch = out_size / (hist * 64);  // 16384

    vfloat4* out4 = (vfloat4*)d_out;

    if (ws_size >= (size_t)(batch + 1) * sizeof(int)) {
        int* row_start = (int*)d_ws;
        build_row_starts<<<(batch + 1 + 255) / 256, 256, 0, stream>>>(pos, n, batch, row_start);
        fill_out<<<batch, 256, 0, stream>>>(emb4, row_start, out4, hist);
    } else {
        fill_out_search<<<batch, 256, 0, stream>>>(emb4, pos, n, out4, hist);
    }
}